// Round 3
// baseline (951.429 us; speedup 1.0000x reference)
//
#include <hip/hip_runtime.h>
#include <float.h>

#define NPTS 8192
#define NB   4
#define COUT 64
#define ROWS 8          // rows per block, one wave each
#define CAP  192

#define ELEM(v,q) ((q)==0?(v).x:(q)==1?(v).y:(q)==2?(v).z:(v).w)

// Block = 512 threads = 8 waves; wave w owns row (n_base + w).
// Phase A: f32 distance screen; each lane keeps top-2 keys of its 128
//          candidates in registers (monotone uint keys; no LDS, no atomics).
// tau:     16-step binary search on high-16 key bits over the 128-entry
//          wave pool (shfl-butterfly counts). pool subset of full set =>
//          pool-40th <= true-40th => {d >= tau} is a superset of top-40.
//          -1e-3 margin covers f32-vs-f64 jitter (~2e-5).
// Phase B: re-stream, collect indices with d32 >= tau (~50-70 per row).
// Exact:   fp64 distance for collected candidates, all-pairs lex rank
//          (val desc, idx asc) == lax.top_k tie-break; rank<40 selected,
//          rank order gives top-10/20 prefixes.
// Epilogue: BN+conv folded to z = a0*p0+a1*p1+a2*p2+K per (s,o); maxpool
//          before LeakyReLU (monotone); stores 32B-coalesced.
__global__ __launch_bounds__(512, 8) void msedge_kernel(
    const float* __restrict__ x,
    const float* __restrict__ W,
    const float* __restrict__ gamma,
    const float* __restrict__ beta,
    const float* __restrict__ rmean,
    const float* __restrict__ rvar,
    float* __restrict__ out)
{
    __shared__ int     col[ROWS][CAP];     // 6 KB
    __shared__ double2 pk[ROWS][CAP];      // 24 KB  (exact dist, idx)
    __shared__ float4  nbx[ROWS][41];      // 5.25 KB (pad 41: conflict-free)
    __shared__ int     ccnt[ROWS];

    const int t    = threadIdx.x;
    const int w    = t >> 6;
    const int lane = t & 63;

    const int blk = blockIdx.x;
    const int swz = (blk & 7) * 512 + (blk >> 3);   // bijective XCD swizzle
    const int row_base = swz * ROWS;
    const int b      = row_base >> 13;
    const int n_base = row_base & (NPTS - 1);
    const int n      = n_base + w;

    const float* __restrict__ xb = x + b * 3 * NPTS;

    if (lane == 0) ccnt[w] = 0;

    const float c0 = xb[n], c1 = xb[NPTS + n], c2 = xb[2 * NPTS + n];
    const float cxx = fmaf(c0, c0, fmaf(c1, c1, c2 * c2));
    const double dc0 = (double)c0, dc1 = (double)c1, dc2 = (double)c2;
    const double dcxx = fma(dc0, dc0, fma(dc1, dc1, dc2 * dc2));

    // ---------------- Phase A: screen, per-lane top-2 keys ----------------
    const int mbase = lane * 128;
    unsigned k0 = 0u, k1 = 0u;             // sorted desc (keys are >= 0)
    for (int it = 0; it < 32; ++it) {
        const int m0 = mbase + 4 * it;
        const float4 a0 = *(const float4*)(xb + m0);
        const float4 a1 = *(const float4*)(xb + NPTS + m0);
        const float4 a2 = *(const float4*)(xb + 2 * NPTS + m0);
#pragma unroll
        for (int q = 0; q < 4; ++q) {
            const float p0 = ELEM(a0, q), p1 = ELEM(a1, q), p2 = ELEM(a2, q);
            const float inner = fmaf(c0, p0, fmaf(c1, p1, c2 * p2));
            const float xxm   = fmaf(p0, p0, fmaf(p1, p1, p2 * p2));
            const float d     = fmaf(2.0f, inner, -cxx) - xxm;   // -||pi-pj||^2
            const unsigned u  = __float_as_uint(d);
            const unsigned key = ((int)u < 0) ? ~u : (u | 0x80000000u);
            const unsigned m1 = min(k0, key);
            k0 = max(k0, key);
            k1 = max(k1, m1);
        }
    }

    // ---------------- tau: binary search on high-16 key bits ----------------
    unsigned lo = 0;
    for (unsigned step = 0x8000u; step; step >>= 1) {
        const unsigned cand = (lo + step) << 16;
        int c = (k0 >= cand ? 1 : 0) + (k1 >= cand ? 1 : 0);
#pragma unroll
        for (int off = 1; off < 64; off <<= 1) c += __shfl_xor(c, off);
        if (c >= 40) lo += step;
    }
    const unsigned tu = lo << 16;
    const unsigned ue = (tu & 0x80000000u) ? (tu & 0x7fffffffu) : ~tu;
    const float tau = __uint_as_float(ue) - 1e-3f;

    // ---------------- Phase B: collect superset ----------------
    asm volatile("s_waitcnt lgkmcnt(0)" ::: "memory");
    for (int it = 0; it < 32; ++it) {
        const int m0 = mbase + 4 * it;
        const float4 a0 = *(const float4*)(xb + m0);
        const float4 a1 = *(const float4*)(xb + NPTS + m0);
        const float4 a2 = *(const float4*)(xb + 2 * NPTS + m0);
#pragma unroll
        for (int q = 0; q < 4; ++q) {
            const float p0 = ELEM(a0, q), p1 = ELEM(a1, q), p2 = ELEM(a2, q);
            const float inner = fmaf(c0, p0, fmaf(c1, p1, c2 * p2));
            const float xxm   = fmaf(p0, p0, fmaf(p1, p1, p2 * p2));
            const float d     = fmaf(2.0f, inner, -cxx) - xxm;
            if (d >= tau) {
                const int p = atomicAdd(&ccnt[w], 1);
                if (p < CAP) col[w][p] = m0 + q;
            }
        }
    }
    asm volatile("s_waitcnt lgkmcnt(0)" ::: "memory");
    int C = ccnt[w]; C = min(C, CAP);

    // ---------------- Exact fp64 distances ----------------
    double exd[3]; int exm[3]; float ep0[3], ep1[3], ep2[3];
#pragma unroll
    for (int q = 0; q < 3; ++q) {
        const int i = lane + 64 * q;
        exm[q] = -1;
        if (i < C) {
            const int m = col[w][i];
            const float p0 = xb[m], p1 = xb[NPTS + m], p2 = xb[2 * NPTS + m];
            ep0[q] = p0; ep1[q] = p1; ep2[q] = p2;
            const double P0 = p0, P1 = p1, P2 = p2;
            const double inner = fma(dc0, P0, fma(dc1, P1, dc2 * P2));
            const double xxm   = fma(P0, P0, fma(P1, P1, P2 * P2));
            const double dd    = 2.0 * inner - dcxx - xxm;
            exd[q] = dd; exm[q] = m;
            double2 v; v.x = dd; v.y = __hiloint2double(0, m);
            pk[w][i] = v;
        }
    }
    asm volatile("s_waitcnt lgkmcnt(0)" ::: "memory");

    // ---------------- All-pairs lex rank ----------------
    int myr[3] = {0, 0, 0};
    for (int j = 0; j < C; ++j) {
        const double2 v = pk[w][j];          // broadcast read
        const double dv = v.x;
        const int    mj = __double2loint(v.y);
#pragma unroll
        for (int q = 0; q < 3; ++q) {
            if (exm[q] >= 0) {
                const bool g = (dv > exd[q]) || (dv == exd[q] && mj < exm[q]);
                myr[q] += g ? 1 : 0;
            }
        }
    }
#pragma unroll
    for (int q = 0; q < 3; ++q)
        if (exm[q] >= 0 && myr[q] < 40)
            nbx[w][myr[q]] = make_float4(ep0[q], ep1[q], ep2[q], 0.0f);

    __syncthreads();

    // ---------------- Fused conv + BN + maxpool + LeakyReLU ----------------
    const int o  = t >> 3;       // 0..63
    const int rr = t & 7;        // row within block
    const int nn = n_base + rr;
    const float cc0 = xb[nn], cc1 = xb[NPTS + nn], cc2 = xb[2 * NPTS + nn];

    float a0_[3], a1_[3], a2_[3], K_[3];
#pragma unroll
    for (int s = 0; s < 3; ++s) {
        const int go = s * COUT + o;
        const float* Wp = W + go * 6;
        const float inv = gamma[go] / sqrtf(rvar[go] + 1e-5f);
        const float sh  = beta[go] - rmean[go] * inv;
        a0_[s] = Wp[0] * inv; a1_[s] = Wp[1] * inv; a2_[s] = Wp[2] * inv;
        const float kc = fmaf(Wp[3] - Wp[0], cc0,
                         fmaf(Wp[4] - Wp[1], cc1, (Wp[5] - Wp[2]) * cc2));
        K_[s] = fmaf(kc, inv, sh);
    }
    float mx0 = -FLT_MAX, mx1 = -FLT_MAX, mx2 = -FLT_MAX;
    for (int j = 0; j < 40; ++j) {
        const float4 v = nbx[rr][j];
        {
            const float z = fmaf(a0_[2], v.x, fmaf(a1_[2], v.y, fmaf(a2_[2], v.z, K_[2])));
            mx2 = fmaxf(mx2, z);
        }
        if (j < 20) {
            const float z = fmaf(a0_[1], v.x, fmaf(a1_[1], v.y, fmaf(a2_[1], v.z, K_[1])));
            mx1 = fmaxf(mx1, z);
        }
        if (j < 10) {
            const float z = fmaf(a0_[0], v.x, fmaf(a1_[0], v.y, fmaf(a2_[0], v.z, K_[0])));
            mx0 = fmaxf(mx0, z);
        }
    }
    mx0 = fmaxf(mx0, 0.2f * mx0);
    mx1 = fmaxf(mx1, 0.2f * mx1);
    mx2 = fmaxf(mx2, 0.2f * mx2);
    out[((0 * NB + b) * COUT + o) * NPTS + nn] = mx0;
    out[((1 * NB + b) * COUT + o) * NPTS + nn] = mx1;
    out[((2 * NB + b) * COUT + o) * NPTS + nn] = mx2;
}

extern "C" void kernel_launch(void* const* d_in, const int* in_sizes, int n_in,
                              void* d_out, int out_size, void* d_ws, size_t ws_size,
                              hipStream_t stream) {
    const float* x     = (const float*)d_in[0];
    const float* W     = (const float*)d_in[1];
    const float* gamma = (const float*)d_in[2];
    const float* beta  = (const float*)d_in[3];
    const float* rmean = (const float*)d_in[4];
    const float* rvar  = (const float*)d_in[5];
    float* out = (float*)d_out;

    msedge_kernel<<<dim3(NB * NPTS / ROWS), dim3(512), 0, stream>>>(
        x, W, gamma, beta, rmean, rvar, out);
}

// Round 4
// 348.357 us; speedup vs baseline: 2.7312x; 2.7312x over previous
//
#include <hip/hip_runtime.h>
#include <float.h>

#define NPTS 8192
#define NB   4
#define COUT 64
#define RPB  16          // rows per block: 8 waves x 2 rows/wave
#define CAP  192

#define ELEM(v,q) ((q)==0?(v).x:(q)==1?(v).y:(q)==2?(v).z:(v).w)

// Block = 512 threads = 8 waves; wave w owns rows 2w and 2w+1 (shared loads).
// Stage:   whole batch x [3][8192] (96 KB) -> LDS once; all passes read LDS.
// Phase A: f32 screen d' = 2*inner - xxm (cxx dropped: constant per row,
//          ordering invariant); per-lane top-2 PER ROW in registers, xyz read
//          once per candidate serves both rows.
// tau:     16-step binary search on high-16 monotone-key bits; counts via
//          __ballot + popcount (scalar pipe, no LDS port).
// Phase B: re-stream from LDS, collect indices with d' >= tau (superset of
//          exact fp64 top-40; margin 1e-3 >> f32 jitter ~2e-5).
// Exact:   fp64 full reference formula for collected candidates; all-pairs
//          lex rank (val desc, idx asc) == lax.top_k; rank<40 -> sorted
//          neighbors, top-10/20 are prefixes.
// Epilogue: BN+conv folded; maxpool before LeakyReLU (monotone).
__global__ __launch_bounds__(512, 2) void msedge_kernel(
    const float* __restrict__ x,
    const float* __restrict__ W,
    const float* __restrict__ gamma,
    const float* __restrict__ beta,
    const float* __restrict__ rmean,
    const float* __restrict__ rvar,
    float* __restrict__ out)
{
    __shared__ float  sx[3 * NPTS];        // 96 KB
    __shared__ double pd[RPB][CAP];        // 24 KB exact distances
    __shared__ int    col[RPB][CAP];       // 12 KB candidate indices
    __shared__ float4 nbx[RPB][41];        // 10.25 KB ranked neighbors (pad 41)
    __shared__ int    ccnt[RPB];

    const int t    = threadIdx.x;
    const int w    = t >> 6;
    const int lane = t & 63;

    const int blk = blockIdx.x;
    const int swz = (blk & 7) * 256 + (blk >> 3);   // bijective XCD swizzle (2048)
    const int row_base = swz * RPB;
    const int b      = row_base >> 13;
    const int n_base = row_base & (NPTS - 1);

    const float* __restrict__ xb = x + b * 3 * NPTS;

    // ---------------- stage 96 KB global -> LDS ----------------
#pragma unroll
    for (int s = 0; s < 12; ++s) {
        const int f = (s * 512 + t) * 4;
        *(float4*)(sx + f) = *(const float4*)(xb + f);
    }
    if (t < RPB) ccnt[t] = 0;
    __syncthreads();

    const int rA = 2 * w, rB = 2 * w + 1;
    const int nA = n_base + rA, nB = n_base + rB;
    const float cA0 = sx[nA], cA1 = sx[NPTS + nA], cA2 = sx[2 * NPTS + nA];
    const float cB0 = sx[nB], cB1 = sx[NPTS + nB], cB2 = sx[2 * NPTS + nB];

    // ---------------- Phase A: screen, per-lane top-2 per row ----------------
    float A0 = -FLT_MAX, A1 = -FLT_MAX;
    float B0 = -FLT_MAX, B1 = -FLT_MAX;
#pragma unroll 4
    for (int it = 0; it < 32; ++it) {
        const int m0 = it * 256 + lane * 4;
        const float4 a0 = *(const float4*)(sx + m0);
        const float4 a1 = *(const float4*)(sx + NPTS + m0);
        const float4 a2 = *(const float4*)(sx + 2 * NPTS + m0);
#pragma unroll
        for (int q = 0; q < 4; ++q) {
            const float p0 = ELEM(a0, q), p1 = ELEM(a1, q), p2 = ELEM(a2, q);
            const float xxm = fmaf(p0, p0, fmaf(p1, p1, p2 * p2));
            const float dA  = fmaf(2.0f, fmaf(cA0, p0, fmaf(cA1, p1, cA2 * p2)), -xxm);
            const float mA  = fminf(A0, dA);
            A0 = fmaxf(A0, dA); A1 = fmaxf(A1, mA);
            const float dB  = fmaf(2.0f, fmaf(cB0, p0, fmaf(cB1, p1, cB2 * p2)), -xxm);
            const float mB  = fminf(B0, dB);
            B0 = fmaxf(B0, dB); B1 = fmaxf(B1, mB);
        }
    }

    // ---------------- tau: ballot binary search on high-16 key bits ----------
    auto mkkey = [](float f) -> unsigned {
        const unsigned u = __float_as_uint(f);
        return ((int)u < 0) ? ~u : (u | 0x80000000u);
    };
    auto find_tau = [&](unsigned K0, unsigned K1) -> float {
        unsigned lo = 0;
        for (unsigned step = 0x8000u; step; step >>= 1) {
            const unsigned cand = (lo + step) << 16;
            const int c = __popcll(__ballot(K0 >= cand)) + __popcll(__ballot(K1 >= cand));
            if (c >= 40) lo += step;
        }
        const unsigned tu = lo << 16;
        const unsigned ue = (tu & 0x80000000u) ? (tu & 0x7fffffffu) : ~tu;
        return __uint_as_float(ue) - 1e-3f;
    };
    const float tauA = find_tau(mkkey(A0), mkkey(A1));
    const float tauB = find_tau(mkkey(B0), mkkey(B1));

    // ---------------- Phase B: collect superset ----------------
#pragma unroll 4
    for (int it = 0; it < 32; ++it) {
        const int m0 = it * 256 + lane * 4;
        const float4 a0 = *(const float4*)(sx + m0);
        const float4 a1 = *(const float4*)(sx + NPTS + m0);
        const float4 a2 = *(const float4*)(sx + 2 * NPTS + m0);
#pragma unroll
        for (int q = 0; q < 4; ++q) {
            const float p0 = ELEM(a0, q), p1 = ELEM(a1, q), p2 = ELEM(a2, q);
            const float xxm = fmaf(p0, p0, fmaf(p1, p1, p2 * p2));
            const float dA  = fmaf(2.0f, fmaf(cA0, p0, fmaf(cA1, p1, cA2 * p2)), -xxm);
            if (dA >= tauA) {
                const int p = atomicAdd(&ccnt[rA], 1);
                if (p < CAP) col[rA][p] = m0 + q;
            }
            const float dB  = fmaf(2.0f, fmaf(cB0, p0, fmaf(cB1, p1, cB2 * p2)), -xxm);
            if (dB >= tauB) {
                const int p = atomicAdd(&ccnt[rB], 1);
                if (p < CAP) col[rB][p] = m0 + q;
            }
        }
    }
    asm volatile("s_waitcnt lgkmcnt(0)" ::: "memory");

    // ---------------- Exact fp64 rank per owned row ----------------
    auto do_row = [&](int row, float c0, float c1, float c2) {
        const double D0 = (double)c0, D1 = (double)c1, D2 = (double)c2;
        const double dcxx = fma(D0, D0, fma(D1, D1, D2 * D2));
        int C = ccnt[row]; C = min(C, CAP);
        double exd[3]; int exm[3]; float e0[3], e1[3], e2[3];
#pragma unroll
        for (int q = 0; q < 3; ++q) {
            const int i = lane + 64 * q;
            exm[q] = -1;
            if (i < C) {
                const int m = col[row][i];
                const float p0 = sx[m], p1 = sx[NPTS + m], p2 = sx[2 * NPTS + m];
                e0[q] = p0; e1[q] = p1; e2[q] = p2;
                const double P0 = p0, P1 = p1, P2 = p2;
                const double inner = fma(D0, P0, fma(D1, P1, D2 * P2));
                const double xxm   = fma(P0, P0, fma(P1, P1, P2 * P2));
                const double dd    = 2.0 * inner - dcxx - xxm;
                exd[q] = dd; exm[q] = m;
                pd[row][i] = dd;
            }
        }
        asm volatile("s_waitcnt lgkmcnt(0)" ::: "memory");
        int r0 = 0, r1 = 0, r2 = 0;
        for (int j = 0; j < C; ++j) {
            const double dv = pd[row][j];      // broadcast reads
            const int    mj = col[row][j];
            if (exm[0] >= 0) r0 += (dv > exd[0] || (dv == exd[0] && mj < exm[0])) ? 1 : 0;
            if (exm[1] >= 0) r1 += (dv > exd[1] || (dv == exd[1] && mj < exm[1])) ? 1 : 0;
            if (exm[2] >= 0) r2 += (dv > exd[2] || (dv == exd[2] && mj < exm[2])) ? 1 : 0;
        }
        if (exm[0] >= 0 && r0 < 40) nbx[row][r0] = make_float4(e0[0], e1[0], e2[0], 0.f);
        if (exm[1] >= 0 && r1 < 40) nbx[row][r1] = make_float4(e0[1], e1[1], e2[1], 0.f);
        if (exm[2] >= 0 && r2 < 40) nbx[row][r2] = make_float4(e0[2], e1[2], e2[2], 0.f);
    };
    do_row(rA, cA0, cA1, cA2);
    do_row(rB, cB0, cB1, cB2);
    __syncthreads();

    // ---------------- Fused conv + BN + maxpool + LeakyReLU ----------------
    const int rr = t & 15;
    const int o0 = t >> 4;           // 0..31; channels o0 and o0+32
    const int nn = n_base + rr;
    const float cc0 = sx[nn], cc1 = sx[NPTS + nn], cc2 = sx[2 * NPTS + nn];

    float a0_[2][3], a1_[2][3], a2_[2][3], K_[2][3];
#pragma unroll
    for (int oo = 0; oo < 2; ++oo) {
        const int o = o0 + 32 * oo;
#pragma unroll
        for (int s = 0; s < 3; ++s) {
            const int go = s * COUT + o;
            const float* Wp = W + go * 6;
            const float inv = gamma[go] / sqrtf(rvar[go] + 1e-5f);
            const float sh  = beta[go] - rmean[go] * inv;
            a0_[oo][s] = Wp[0] * inv; a1_[oo][s] = Wp[1] * inv; a2_[oo][s] = Wp[2] * inv;
            const float kc = fmaf(Wp[3] - Wp[0], cc0,
                             fmaf(Wp[4] - Wp[1], cc1, (Wp[5] - Wp[2]) * cc2));
            K_[oo][s] = fmaf(kc, inv, sh);
        }
    }
    float mx[2][3];
#pragma unroll
    for (int oo = 0; oo < 2; ++oo)
#pragma unroll
        for (int s = 0; s < 3; ++s) mx[oo][s] = -FLT_MAX;

    for (int j = 0; j < 40; ++j) {
        const float4 v = nbx[rr][j];
#pragma unroll
        for (int oo = 0; oo < 2; ++oo) {
            {
                const float z = fmaf(a0_[oo][2], v.x, fmaf(a1_[oo][2], v.y,
                                fmaf(a2_[oo][2], v.z, K_[oo][2])));
                mx[oo][2] = fmaxf(mx[oo][2], z);
            }
            if (j < 20) {
                const float z = fmaf(a0_[oo][1], v.x, fmaf(a1_[oo][1], v.y,
                                fmaf(a2_[oo][1], v.z, K_[oo][1])));
                mx[oo][1] = fmaxf(mx[oo][1], z);
            }
            if (j < 10) {
                const float z = fmaf(a0_[oo][0], v.x, fmaf(a1_[oo][0], v.y,
                                fmaf(a2_[oo][0], v.z, K_[oo][0])));
                mx[oo][0] = fmaxf(mx[oo][0], z);
            }
        }
    }
#pragma unroll
    for (int oo = 0; oo < 2; ++oo) {
        const int o = o0 + 32 * oo;
#pragma unroll
        for (int s = 0; s < 3; ++s) {
            const float m = mx[oo][s];
            out[((s * NB + b) * COUT + o) * NPTS + nn] = fmaxf(m, 0.2f * m);
        }
    }
}

extern "C" void kernel_launch(void* const* d_in, const int* in_sizes, int n_in,
                              void* d_out, int out_size, void* d_ws, size_t ws_size,
                              hipStream_t stream) {
    const float* x     = (const float*)d_in[0];
    const float* W     = (const float*)d_in[1];
    const float* gamma = (const float*)d_in[2];
    const float* beta  = (const float*)d_in[3];
    const float* rmean = (const float*)d_in[4];
    const float* rvar  = (const float*)d_in[5];
    float* out = (float*)d_out;

    msedge_kernel<<<dim3(NB * NPTS / RPB), dim3(512), 0, stream>>>(
        x, W, gamma, beta, rmean, rvar, out);
}

// Round 5
// 202.168 us; speedup vs baseline: 4.7061x; 1.7231x over previous
//
#include <hip/hip_runtime.h>
#include <float.h>

#define NPTS 8192
#define NB   4
#define COUT 64
#define RPB  64          // rows per block (16 waves x 4 rows)
#define RPW  4
#define CAP  192

#define ELEM(v,q) ((q)==0?(v).x:(q)==1?(v).y:(q)==2?(v).z:(v).w)

// Block = 1024 threads = 16 waves, one block per CU; wave w owns rows 4w..4w+3.
// Stage:   batch x [3][8192] (96 KB) -> LDS.
// Phase A: f32 screen d' = 2*inner - xxm; per (lane,row) keep MAX over 4
//          disjoint tile-substreams (1 v_max per cand per row). Pool/row =
//          256 distinct subset-maxima => pool-40th <= true-40th.
// tau:     20-bit ballot binary search on monotone f32 keys, -1e-3 margin.
// Phase B: re-stream, collect indices with d' >= tau (superset of fp64 top-40).
// Exact:   fp64 reference distance for collected; key = (sortbits>>13<<13) |
//          (8191-m)  => single u64 compare == (val desc, idx asc) lex rank.
// Epilogue: BN+conv folded; maxpool prefixes j<10/20/40; LeakyReLU after max.
__global__ __launch_bounds__(1024) void msedge_kernel(
    const float* __restrict__ x,
    const float* __restrict__ W,
    const float* __restrict__ gamma,
    const float* __restrict__ beta,
    const float* __restrict__ rmean,
    const float* __restrict__ rvar,
    float* __restrict__ out)
{
    __shared__ float sx[3 * NPTS];                     // 96 KB
    __shared__ unsigned long long pdcol[16][CAP];      // 24 KB union: col u16 / pd u64
    __shared__ float nb0[RPB][41], nb1[RPB][41], nb2[RPB][41];  // 30.75 KB
    __shared__ unsigned ccnt[RPB];

    const int t    = threadIdx.x;
    const int w    = t >> 6;
    const int lane = t & 63;

    const int blk = blockIdx.x;
    const int swz = (blk & 7) * 64 + (blk >> 3);       // bijective XCD swizzle (512)
    const int row_base = swz * RPB;
    const int b      = row_base >> 13;
    const int n_base = row_base & (NPTS - 1);

    const float* __restrict__ xb = x + b * 3 * NPTS;

    // ---------------- stage 96 KB global -> LDS ----------------
#pragma unroll
    for (int s = 0; s < 6; ++s) {
        const int f = (s * 1024 + t) * 4;
        *(float4*)(sx + f) = *(const float4*)(xb + f);
    }
    if (t < RPB) ccnt[t] = 0;
    __syncthreads();

    float c0[RPW], c1[RPW], c2[RPW];
#pragma unroll
    for (int r = 0; r < RPW; ++r) {
        const int n = n_base + 4 * w + r;
        c0[r] = sx[n]; c1[r] = sx[NPTS + n]; c2[r] = sx[2 * NPTS + n];
    }

    // ---------------- Phase A: substream-max screen ----------------
    float sub[RPW][4];
#pragma unroll
    for (int r = 0; r < RPW; ++r)
#pragma unroll
        for (int u = 0; u < 4; ++u) sub[r][u] = -FLT_MAX;

    for (int it2 = 0; it2 < 8; ++it2) {
#pragma unroll
        for (int u = 0; u < 4; ++u) {
            const int m0 = (it2 * 4 + u) * 256 + lane * 4;
            const float4 a0 = *(const float4*)(sx + m0);
            const float4 a1 = *(const float4*)(sx + NPTS + m0);
            const float4 a2 = *(const float4*)(sx + 2 * NPTS + m0);
#pragma unroll
            for (int q = 0; q < 4; ++q) {
                const float p0 = ELEM(a0, q), p1 = ELEM(a1, q), p2 = ELEM(a2, q);
                const float xxm = fmaf(p0, p0, fmaf(p1, p1, p2 * p2));
#pragma unroll
                for (int r = 0; r < RPW; ++r) {
                    const float d = fmaf(2.0f,
                        fmaf(c0[r], p0, fmaf(c1[r], p1, c2[r] * p2)), -xxm);
                    sub[r][u] = fmaxf(sub[r][u], d);
                }
            }
        }
    }

    // ---------------- tau: 20-bit ballot binary search ----------------
    auto mkkey = [](float f) -> unsigned {
        const unsigned u = __float_as_uint(f);
        return ((int)u < 0) ? ~u : (u | 0x80000000u);
    };
    float tau[RPW];
#pragma unroll
    for (int r = 0; r < RPW; ++r) {
        const unsigned k0 = mkkey(sub[r][0]), k1 = mkkey(sub[r][1]);
        const unsigned k2 = mkkey(sub[r][2]), k3 = mkkey(sub[r][3]);
        unsigned lo = 0;
        for (unsigned bit = 0x80000u; bit; bit >>= 1) {
            const unsigned cand = (lo | bit) << 12;
            const int c = __popcll(__ballot(k0 >= cand)) + __popcll(__ballot(k1 >= cand))
                        + __popcll(__ballot(k2 >= cand)) + __popcll(__ballot(k3 >= cand));
            if (c >= 40) lo |= bit;
        }
        const unsigned tu = lo << 12;
        const unsigned ue = (tu & 0x80000000u) ? (tu & 0x7fffffffu) : ~tu;
        tau[r] = __uint_as_float(ue) - 1e-3f;
    }

    // ---------------- Phase B: collect superset ----------------
    unsigned short* const colp = (unsigned short*)&pdcol[w][0];   // [RPW][CAP] u16
#pragma unroll 2
    for (int it = 0; it < 32; ++it) {
        const int m0 = it * 256 + lane * 4;
        const float4 a0 = *(const float4*)(sx + m0);
        const float4 a1 = *(const float4*)(sx + NPTS + m0);
        const float4 a2 = *(const float4*)(sx + 2 * NPTS + m0);
#pragma unroll
        for (int q = 0; q < 4; ++q) {
            const float p0 = ELEM(a0, q), p1 = ELEM(a1, q), p2 = ELEM(a2, q);
            const float xxm = fmaf(p0, p0, fmaf(p1, p1, p2 * p2));
#pragma unroll
            for (int r = 0; r < RPW; ++r) {
                const float d = fmaf(2.0f,
                    fmaf(c0[r], p0, fmaf(c1[r], p1, c2[r] * p2)), -xxm);
                if (d >= tau[r]) {
                    const unsigned p = atomicAdd(&ccnt[4 * w + r], 1u);
                    if (p < CAP) colp[r * CAP + p] = (unsigned short)(m0 + q);
                }
            }
        }
    }
    asm volatile("s_waitcnt lgkmcnt(0)" ::: "memory");

    // cache counts + candidate indices BEFORE pd overlay overwrites col
    int C[RPW];
    unsigned short myi[RPW][3];
#pragma unroll
    for (int r = 0; r < RPW; ++r) {
        C[r] = min((int)ccnt[4 * w + r], CAP);
#pragma unroll
        for (int q = 0; q < 3; ++q) {
            const int i = lane + 64 * q;
            myi[r][q] = (i < C[r]) ? colp[r * CAP + i] : (unsigned short)0xFFFF;
        }
    }
    asm volatile("s_waitcnt lgkmcnt(0)" ::: "memory");

    // ---------------- per-row exact fp64 + u64-key rank ----------------
    unsigned long long* const pdw = &pdcol[w][0];
#pragma unroll 1
    for (int r = 0; r < RPW; ++r) {
        const double D0 = (double)c0[r], D1 = (double)c1[r], D2 = (double)c2[r];
        const double dcxx = fma(D0, D0, fma(D1, D1, D2 * D2));
        const int Cr = C[r];
        unsigned long long mykey[3];
        float e0[3], e1[3], e2[3];
        bool valid[3];
#pragma unroll
        for (int q = 0; q < 3; ++q) {
            valid[q] = (myi[r][q] != 0xFFFF);
            mykey[q] = ~0ull;
            if (valid[q]) {
                const int m = myi[r][q];
                const float p0 = sx[m], p1 = sx[NPTS + m], p2 = sx[2 * NPTS + m];
                e0[q] = p0; e1[q] = p1; e2[q] = p2;
                const double P0 = p0, P1 = p1, P2 = p2;
                const double inner = fma(D0, P0, fma(D1, P1, D2 * P2));
                const double xxm   = fma(P0, P0, fma(P1, P1, P2 * P2));
                const double dd    = 2.0 * inner - dcxx - xxm;
                const unsigned long long bl = (unsigned long long)__double_as_longlong(dd);
                const unsigned long long tt =
                    bl ^ ((unsigned long long)(((long long)bl) >> 63) | 0x8000000000000000ull);
                const unsigned long long key = (tt & ~8191ull) | (unsigned long long)(8191 - m);
                mykey[q] = key;
                pdw[lane + 64 * q] = key;
            }
        }
        if ((Cr & 1) && lane == 0) pdw[Cr] = 0ull;    // pad for paired reads
        asm volatile("s_waitcnt lgkmcnt(0)" ::: "memory");

        int rk0 = 0, rk1 = 0, rk2 = 0;
        for (int j = 0; j < Cr; j += 2) {
            const ulonglong2 kk = *(const ulonglong2*)&pdw[j];
            rk0 += (kk.x > mykey[0]) + (kk.y > mykey[0]);
            rk1 += (kk.x > mykey[1]) + (kk.y > mykey[1]);
            rk2 += (kk.x > mykey[2]) + (kk.y > mykey[2]);
        }
        const int R = 4 * w + r;
        if (valid[0] && rk0 < 40) { nb0[R][rk0] = e0[0]; nb1[R][rk0] = e1[0]; nb2[R][rk0] = e2[0]; }
        if (valid[1] && rk1 < 40) { nb0[R][rk1] = e0[1]; nb1[R][rk1] = e1[1]; nb2[R][rk1] = e2[1]; }
        if (valid[2] && rk2 < 40) { nb0[R][rk2] = e0[2]; nb1[R][rk2] = e1[2]; nb2[R][rk2] = e2[2]; }
        asm volatile("s_waitcnt lgkmcnt(0)" ::: "memory");
    }
    __syncthreads();

    // ---------------- Fused conv + BN + maxpool + LeakyReLU ----------------
    const int R  = lane;                 // row within block
    const int nn = n_base + R;
    const float cc0 = sx[nn], cc1 = sx[NPTS + nn], cc2 = sx[2 * NPTS + nn];

    float a0_[4][3], a1_[4][3], a2_[4][3], K_[4][3], mx[4][3];
#pragma unroll
    for (int c = 0; c < 4; ++c) {
        const int o = 4 * w + c;
#pragma unroll
        for (int s = 0; s < 3; ++s) {
            const int go = s * COUT + o;
            const float* Wp = W + go * 6;
            const float inv = gamma[go] / sqrtf(rvar[go] + 1e-5f);
            const float sh  = beta[go] - rmean[go] * inv;
            a0_[c][s] = Wp[0] * inv; a1_[c][s] = Wp[1] * inv; a2_[c][s] = Wp[2] * inv;
            const float kc = fmaf(Wp[3] - Wp[0], cc0,
                             fmaf(Wp[4] - Wp[1], cc1, (Wp[5] - Wp[2]) * cc2));
            K_[c][s] = fmaf(kc, inv, sh);
            mx[c][s] = -FLT_MAX;
        }
    }
#pragma unroll 2
    for (int j = 0; j < 10; ++j) {
        const float v0 = nb0[R][j], v1 = nb1[R][j], v2 = nb2[R][j];
#pragma unroll
        for (int c = 0; c < 4; ++c)
#pragma unroll
            for (int s = 0; s < 3; ++s)
                mx[c][s] = fmaxf(mx[c][s],
                    fmaf(a0_[c][s], v0, fmaf(a1_[c][s], v1, fmaf(a2_[c][s], v2, K_[c][s]))));
    }
#pragma unroll 2
    for (int j = 10; j < 20; ++j) {
        const float v0 = nb0[R][j], v1 = nb1[R][j], v2 = nb2[R][j];
#pragma unroll
        for (int c = 0; c < 4; ++c)
#pragma unroll
            for (int s = 1; s < 3; ++s)
                mx[c][s] = fmaxf(mx[c][s],
                    fmaf(a0_[c][s], v0, fmaf(a1_[c][s], v1, fmaf(a2_[c][s], v2, K_[c][s]))));
    }
#pragma unroll 2
    for (int j = 20; j < 40; ++j) {
        const float v0 = nb0[R][j], v1 = nb1[R][j], v2 = nb2[R][j];
#pragma unroll
        for (int c = 0; c < 4; ++c)
            mx[c][2] = fmaxf(mx[c][2],
                fmaf(a0_[c][2], v0, fmaf(a1_[c][2], v1, fmaf(a2_[c][2], v2, K_[c][2]))));
    }
#pragma unroll
    for (int c = 0; c < 4; ++c) {
        const int o = 4 * w + c;
#pragma unroll
        for (int s = 0; s < 3; ++s) {
            const float m = mx[c][s];
            out[((s * NB + b) * COUT + o) * NPTS + nn] = fmaxf(m, 0.2f * m);
        }
    }
}

extern "C" void kernel_launch(void* const* d_in, const int* in_sizes, int n_in,
                              void* d_out, int out_size, void* d_ws, size_t ws_size,
                              hipStream_t stream) {
    const float* x     = (const float*)d_in[0];
    const float* W     = (const float*)d_in[1];
    const float* gamma = (const float*)d_in[2];
    const float* beta  = (const float*)d_in[3];
    const float* rmean = (const float*)d_in[4];
    const float* rvar  = (const float*)d_in[5];
    float* out = (float*)d_out;

    msedge_kernel<<<dim3(NB * NPTS / RPB), dim3(1024), 0, stream>>>(
        x, W, gamma, beta, rmean, rvar, out);
}

// Round 6
// 182.301 us; speedup vs baseline: 5.2190x; 1.1090x over previous
//
#include <hip/hip_runtime.h>
#include <float.h>

#define NPTS 8192
#define NB   4
#define COUT 64
#define WAVES 16
#define RPW  8           // rows per wave
#define RPB  128         // rows per block (16 waves x 8) -> 256 blocks = 1 round
#define CAP  112

#define ELEM(v,q) ((q)==0?(v).x:(q)==1?(v).y:(q)==2?(v).z:(v).w)

// LDS layout (162304 B total):
//  [0,98304)        sx f32[3][8192]           | after screen: pd u64[16][128] @0,
//                                             |   nb0/1/2 f32[128][41] @16384,+20992,+41984
//  [98304,131072)   nsxx f32[8192] = -||p||^2/2
//  [131072,159744)  col u16[128][112]         | after exact: wf f32[3][64][8] @131072
//  [159744,161792)  cs float4[128] (centers)
//  [161792,162304)  ccnt u32[128]
//
// Screen: d~ = c.p - ||p||^2/2 (per-row-constant cxx dropped; ordering invariant).
// Phase A: per (lane,row) max over 4 disjoint substreams -> 256-elem pool/row;
//          pool-40th <= true-40th. tau: 16-step ballot bisection on high-16
//          monotone key bits, -1e-3 margin (>> f32 chain error ~2e-5).
// Phase B: re-stream; group-of-4 max pre-check, then per-hit LDS-atomic append.
// Exact:   f64 reference distance (coords re-read from global; sx is dead),
//          u64 key = (sortbits & ~8191) | (8191-m) -> one-compare lex rank
//          == lax.top_k (val desc, idx asc). rank<40 -> sorted neighbor list.
// Epilogue: folded BN+conv (A.v + K), maxpool over j<10/20/40 prefix, then
//          LeakyReLU (monotone); 8 threads/row, 128-wide coalesced stores.
__global__ __launch_bounds__(1024) void msedge_kernel(
    const float* __restrict__ x,
    const float* __restrict__ W,
    const float* __restrict__ gamma,
    const float* __restrict__ beta,
    const float* __restrict__ rmean,
    const float* __restrict__ rvar,
    float* __restrict__ out)
{
    __shared__ __align__(16) char smem[162304];
    float* const sx   = (float*)smem;
    float* const nsxx = (float*)(smem + 98304);
    unsigned short* const col = (unsigned short*)(smem + 131072);
    float4* const cs  = (float4*)(smem + 159744);
    unsigned* const ccnt = (unsigned*)(smem + 161792);

    const int t = threadIdx.x, w = t >> 6, lane = t & 63;
    const int blk = blockIdx.x;
    const int swz = (blk & 7) * 32 + (blk >> 3);    // bijective XCD swizzle (256)
    const int b = swz >> 6;
    const int n_base = (swz & 63) * RPB;
    const float* __restrict__ xb = x + b * 3 * NPTS;

    // ---------------- stage 96 KB -> LDS ----------------
#pragma unroll
    for (int s = 0; s < 6; ++s) {
        const int f = (s * 1024 + t) * 4;
        *(float4*)(sx + f) = *(const float4*)(xb + f);
    }
    if (t < RPB) ccnt[t] = 0;
    __syncthreads();

    // nsxx = -0.5*||p||^2 ; centers table
#pragma unroll
    for (int g = 0; g < 2; ++g) {
        const int m0 = (g * 1024 + t) * 4;
        const float4 a0 = *(const float4*)(sx + m0);
        const float4 a1 = *(const float4*)(sx + NPTS + m0);
        const float4 a2 = *(const float4*)(sx + 2 * NPTS + m0);
        float4 r;
        r.x = -0.5f * fmaf(a0.x, a0.x, fmaf(a1.x, a1.x, a2.x * a2.x));
        r.y = -0.5f * fmaf(a0.y, a0.y, fmaf(a1.y, a1.y, a2.y * a2.y));
        r.z = -0.5f * fmaf(a0.z, a0.z, fmaf(a1.z, a1.z, a2.z * a2.z));
        r.w = -0.5f * fmaf(a0.w, a0.w, fmaf(a1.w, a1.w, a2.w * a2.w));
        *(float4*)(nsxx + m0) = r;
    }
    if (t < RPB) {
        const int n = n_base + t;
        cs[t] = make_float4(sx[n], sx[NPTS + n], sx[2 * NPTS + n], 0.f);
    }
    __syncthreads();

    float c0[RPW], c1[RPW], c2[RPW], tau[RPW];
#pragma unroll
    for (int r = 0; r < RPW; ++r) {
        const float4 cc = cs[w * RPW + r];
        c0[r] = cc.x; c1[r] = cc.y; c2[r] = cc.z;
    }

    // ---------------- Phase A: substream-max screen ----------------
    float sub[RPW][4];
#pragma unroll
    for (int r = 0; r < RPW; ++r) { sub[r][0] = sub[r][1] = sub[r][2] = sub[r][3] = -FLT_MAX; }

    for (int it2 = 0; it2 < 8; ++it2) {
#pragma unroll
        for (int u = 0; u < 4; ++u) {
            const int m0 = (it2 * 4 + u) * 256 + lane * 4;
            const float4 a0 = *(const float4*)(sx + m0);
            const float4 a1 = *(const float4*)(sx + NPTS + m0);
            const float4 a2 = *(const float4*)(sx + 2 * NPTS + m0);
            const float4 ns = *(const float4*)(nsxx + m0);
#pragma unroll
            for (int q = 0; q < 4; ++q) {
                const float p0 = ELEM(a0, q), p1 = ELEM(a1, q), p2 = ELEM(a2, q);
                const float nq = ELEM(ns, q);
#pragma unroll
                for (int r = 0; r < RPW; ++r) {
                    const float d = fmaf(c0[r], p0, fmaf(c1[r], p1, fmaf(c2[r], p2, nq)));
                    sub[r][u] = fmaxf(sub[r][u], d);
                }
            }
        }
    }

    // ---------------- tau: 16-bit ballot bisection ----------------
    auto mkkey = [](float f) -> unsigned {
        const unsigned u = __float_as_uint(f);
        return ((int)u < 0) ? ~u : (u | 0x80000000u);
    };
#pragma unroll
    for (int r = 0; r < RPW; ++r) {
        const unsigned k0 = mkkey(sub[r][0]), k1 = mkkey(sub[r][1]);
        const unsigned k2 = mkkey(sub[r][2]), k3 = mkkey(sub[r][3]);
        unsigned lo = 0;
        for (unsigned step = 0x8000u; step; step >>= 1) {
            const unsigned cand = (lo | step) << 16;
            const int c = __popcll(__ballot(k0 >= cand)) + __popcll(__ballot(k1 >= cand))
                        + __popcll(__ballot(k2 >= cand)) + __popcll(__ballot(k3 >= cand));
            if (c >= 40) lo |= step;
        }
        const unsigned tu = lo << 16;
        const unsigned ue = (tu & 0x80000000u) ? (tu & 0x7fffffffu) : ~tu;
        tau[r] = __uint_as_float(ue) - 1e-3f;
    }

    // ---------------- Phase B: collect superset ----------------
#pragma unroll 2
    for (int it = 0; it < 32; ++it) {
        const int m0 = it * 256 + lane * 4;
        const float4 a0 = *(const float4*)(sx + m0);
        const float4 a1 = *(const float4*)(sx + NPTS + m0);
        const float4 a2 = *(const float4*)(sx + 2 * NPTS + m0);
        const float4 ns = *(const float4*)(nsxx + m0);
#pragma unroll
        for (int r = 0; r < RPW; ++r) {
            const float d0 = fmaf(c0[r], a0.x, fmaf(c1[r], a1.x, fmaf(c2[r], a2.x, ns.x)));
            const float d1 = fmaf(c0[r], a0.y, fmaf(c1[r], a1.y, fmaf(c2[r], a2.y, ns.y)));
            const float d2 = fmaf(c0[r], a0.z, fmaf(c1[r], a1.z, fmaf(c2[r], a2.z, ns.z)));
            const float d3 = fmaf(c0[r], a0.w, fmaf(c1[r], a1.w, fmaf(c2[r], a2.w, ns.w)));
            const float g = fmaxf(fmaxf(d0, d1), fmaxf(d2, d3));
            if (g >= tau[r]) {
                const int row = w * RPW + r;
                if (d0 >= tau[r]) { const unsigned p = atomicAdd(&ccnt[row], 1u); if (p < CAP) col[row*CAP+p] = (unsigned short)(m0);   }
                if (d1 >= tau[r]) { const unsigned p = atomicAdd(&ccnt[row], 1u); if (p < CAP) col[row*CAP+p] = (unsigned short)(m0+1); }
                if (d2 >= tau[r]) { const unsigned p = atomicAdd(&ccnt[row], 1u); if (p < CAP) col[row*CAP+p] = (unsigned short)(m0+2); }
                if (d3 >= tau[r]) { const unsigned p = atomicAdd(&ccnt[row], 1u); if (p < CAP) col[row*CAP+p] = (unsigned short)(m0+3); }
            }
        }
    }
    __syncthreads();   // screen done everywhere; sx/nsxx dead

    // ---------------- Exact f64 + u64-key rank (per wave, 8 rows) ----------------
    unsigned long long* const pdw = (unsigned long long*)smem + (size_t)w * 128;
    float* const nb0 = (float*)(smem + 16384);
    float* const nb1 = (float*)(smem + 16384 + 20992);
    float* const nb2 = (float*)(smem + 16384 + 41984);

#pragma unroll 1
    for (int r = 0; r < RPW; ++r) {
        const int row = w * RPW + r;
        const int C = min((int)ccnt[row], CAP);
        const double D0 = (double)c0[r], D1 = (double)c1[r], D2 = (double)c2[r];
        const double dcxx = fma(D0, D0, fma(D1, D1, D2 * D2));
        unsigned long long mykey[2]; float e0[2], e1[2], e2[2]; bool val[2];
#pragma unroll
        for (int q = 0; q < 2; ++q) {
            const int i = lane + 64 * q;
            val[q] = (i < C); mykey[q] = 0ull;
            if (val[q]) {
                const int m = col[row * CAP + i];
                const float p0 = xb[m], p1 = xb[NPTS + m], p2 = xb[2 * NPTS + m];
                e0[q] = p0; e1[q] = p1; e2[q] = p2;
                const double P0 = p0, P1 = p1, P2 = p2;
                const double inner = fma(D0, P0, fma(D1, P1, D2 * P2));
                const double xxm   = fma(P0, P0, fma(P1, P1, P2 * P2));
                const double dd    = 2.0 * inner - dcxx - xxm;
                const unsigned long long bl = (unsigned long long)__double_as_longlong(dd);
                const unsigned long long tt =
                    bl ^ ((unsigned long long)(((long long)bl) >> 63) | 0x8000000000000000ull);
                mykey[q] = (tt & ~8191ull) | (unsigned long long)(8191 - m);
                pdw[i] = mykey[q];
            }
        }
        if ((C & 1) && lane == 0) pdw[C] = 0ull;
        asm volatile("s_waitcnt lgkmcnt(0)" ::: "memory");

        int rk0 = 0, rk1 = 0;
        for (int j = 0; j < C; j += 2) {
            const ulonglong2 kk = *(const ulonglong2*)&pdw[j];
            rk0 += (kk.x > mykey[0]) + (kk.y > mykey[0]);
            rk1 += (kk.x > mykey[1]) + (kk.y > mykey[1]);
        }
        if (val[0] && rk0 < 40) { nb0[row*41+rk0] = e0[0]; nb1[row*41+rk0] = e1[0]; nb2[row*41+rk0] = e2[0]; }
        if (val[1] && rk1 < 40) { nb0[row*41+rk1] = e0[1]; nb1[row*41+rk1] = e1[1]; nb2[row*41+rk1] = e2[1]; }
        asm volatile("s_waitcnt lgkmcnt(0)" ::: "memory");
    }
    __syncthreads();

    // ---------------- folded-weight table ----------------
    float* const wf = (float*)(smem + 131072);   // overlays dead col
    if (t < 3 * COUT) {
        const int s = t >> 6, o = t & 63, go = s * COUT + o;
        const float* Wp = W + go * 6;
        const float inv = gamma[go] / sqrtf(rvar[go] + 1e-5f);
        const float sh  = beta[go] - rmean[go] * inv;
        float* d = wf + go * 8;
        d[0] = Wp[0] * inv; d[1] = Wp[1] * inv; d[2] = Wp[2] * inv;
        d[3] = (Wp[3] - Wp[0]) * inv; d[4] = (Wp[4] - Wp[1]) * inv; d[5] = (Wp[5] - Wp[2]) * inv;
        d[6] = sh; d[7] = 0.f;
    }
    __syncthreads();

    // ---------------- fused conv + BN + maxpool + LeakyReLU ----------------
    const int rr = t & 127, cg = t >> 7;     // 8 threads/row, 8 channels each
    const int nn = n_base + rr;
    const float4 c = cs[rr];
#pragma unroll
    for (int s = 0; s < 3; ++s) {
        float A0[8], A1[8], A2[8], Kk[8], mx[8];
#pragma unroll
        for (int k = 0; k < 8; ++k) {
            const float* d = wf + (s * COUT + cg * 8 + k) * 8;
            A0[k] = d[0]; A1[k] = d[1]; A2[k] = d[2];
            Kk[k] = fmaf(d[3], c.x, fmaf(d[4], c.y, fmaf(d[5], c.z, d[6])));
            mx[k] = -FLT_MAX;
        }
        const int ks = (s == 0) ? 10 : (s == 1) ? 20 : 40;
        for (int j = 0; j < ks; ++j) {
            const float v0 = nb0[rr*41+j], v1 = nb1[rr*41+j], v2 = nb2[rr*41+j];
#pragma unroll
            for (int k = 0; k < 8; ++k)
                mx[k] = fmaxf(mx[k], fmaf(A0[k], v0, fmaf(A1[k], v1, fmaf(A2[k], v2, Kk[k]))));
        }
#pragma unroll
        for (int k = 0; k < 8; ++k) {
            const float m = mx[k];
            out[((s * NB + b) * COUT + cg * 8 + k) * NPTS + nn] = fmaxf(m, 0.2f * m);
        }
    }
}

extern "C" void kernel_launch(void* const* d_in, const int* in_sizes, int n_in,
                              void* d_out, int out_size, void* d_ws, size_t ws_size,
                              hipStream_t stream) {
    const float* x     = (const float*)d_in[0];
    const float* W     = (const float*)d_in[1];
    const float* gamma = (const float*)d_in[2];
    const float* beta  = (const float*)d_in[3];
    const float* rmean = (const float*)d_in[4];
    const float* rvar  = (const float*)d_in[5];
    float* out = (float*)d_out;

    msedge_kernel<<<dim3(NB * NPTS / RPB), dim3(1024), 0, stream>>>(
        x, W, gamma, beta, rmean, rvar, out);
}